// Round 2
// baseline (643.760 us; speedup 1.0000x reference)
//
#include <hip/hip_runtime.h>
#include <hip/hip_bf16.h>

typedef __attribute__((ext_vector_type(8))) short short8;
typedef __attribute__((ext_vector_type(4))) float f32x4;

constexpr int Bc = 4, Hc = 16, Sc = 2048, Dc = 128;
constexpr int QT = 64;   // q rows per block (4 waves x 16)
constexpr int KT = 32;   // kv columns per tile
// reference: softmax((masked scores) * 1/sqrt(D)); fold scale and log2(e)
constexpr float SCALE_LOG2E = 0.08838834764831845f * 1.4426950408889634f;

__device__ inline ushort bf16r(float x) {
  __hip_bfloat16 h = __float2bfloat16(x);
  return *reinterpret_cast<ushort*>(&h);
}

__global__ __launch_bounds__(256, 2)
void attn_fwd_kernel(const float* __restrict__ Qg, const float* __restrict__ Kg,
                     const float* __restrict__ Vg, const int* __restrict__ padg,
                     float* __restrict__ Og) {
  const int bh = blockIdx.y;          // 0..63  (b*H + h)
  const int b  = bh >> 4;             // H = 16
  const int qt = blockIdx.x;          // 0..31
  const int tid = threadIdx.x;
  const int wid = tid >> 6;           // wave 0..3
  const int lane = tid & 63;
  const int lg = lane >> 4;           // lane group 0..3
  const int lr = lane & 15;           // lane row 0..15

  const size_t base = (size_t)bh * Sc * Dc;
  const float* Qb = Qg + base;
  const float* Kb = Kg + base;
  const float* Vb = Vg + base;
  const int* padb = padg + b * Sc;

  __shared__ ushort K_lds[KT][136];        // 32 x 128 bf16, row padded (+8)
  __shared__ ushort Vt_lds[Dc][40];        // transposed V: [d][kv], padded
  __shared__ ushort P_lds[4][16][40];      // per-wave P tile, padded

  const int q0 = qt * QT + wid * 16;       // this wave's q rows: q0..q0+15

  // Q fragments: lane holds Q[q0+lr][c*32 + lg*8 + i] as bf16, i=0..7
  short8 aq[4];
  #pragma unroll
  for (int c = 0; c < 4; ++c) {
    const float* gq = Qb + (size_t)(q0 + lr) * Dc + c * 32 + lg * 8;
    f32x4 q0v = *reinterpret_cast<const f32x4*>(gq);
    f32x4 q1v = *reinterpret_cast<const f32x4*>(gq + 4);
    short8 t;
    #pragma unroll
    for (int j = 0; j < 4; ++j) {
      t[j]     = (short)bf16r(q0v[j]);
      t[4 + j] = (short)bf16r(q1v[j]);
    }
    aq[c] = t;
  }

  f32x4 o_acc[8];
  #pragma unroll
  for (int i = 0; i < 8; ++i) o_acc[i] = {0.f, 0.f, 0.f, 0.f};
  float m_run[4], l_run[4];
  #pragma unroll
  for (int r = 0; r < 4; ++r) { m_run[r] = -__builtin_inff(); l_run[r] = 0.f; }

  const int kv_end = qt * QT + QT;         // causal: stop at block diagonal
  for (int kv0 = 0; kv0 < kv_end; kv0 += KT) {
    __syncthreads();                       // protect prior-iter LDS reads
    {
      // stage K tile [32][128] and V^T tile [128][32]; 16 f32 per thread each
      const int r = tid >> 3;              // 0..31
      const int c = (tid & 7) * 16;        // 0,16,...,112
      const float* gk = Kb + (size_t)(kv0 + r) * Dc + c;
      ushort kb[16];
      #pragma unroll
      for (int j4 = 0; j4 < 4; ++j4) {
        f32x4 kv = *reinterpret_cast<const f32x4*>(gk + j4 * 4);
        #pragma unroll
        for (int j = 0; j < 4; ++j) kb[j4 * 4 + j] = bf16r(kv[j]);
      }
      #pragma unroll
      for (int j = 0; j < 16; ++j) K_lds[r][c + j] = kb[j];

      const float* gv = Vb + (size_t)(kv0 + r) * Dc + c;
      #pragma unroll
      for (int j4 = 0; j4 < 4; ++j4) {
        f32x4 vv = *reinterpret_cast<const f32x4*>(gv + j4 * 4);
        #pragma unroll
        for (int j = 0; j < 4; ++j) Vt_lds[c + j4 * 4 + j][r] = bf16r(vv[j]);
      }
    }
    __syncthreads();

    // S tile = Q(16x128) . K^T(128x32): two 16x16 C tiles, K-dim in 4 chunks
    f32x4 s0 = {0.f, 0.f, 0.f, 0.f}, s1 = {0.f, 0.f, 0.f, 0.f};
    #pragma unroll
    for (int c = 0; c < 4; ++c) {
      short8 bk0 = *reinterpret_cast<const short8*>(&K_lds[lr][c * 32 + lg * 8]);
      short8 bk1 = *reinterpret_cast<const short8*>(&K_lds[16 + lr][c * 32 + lg * 8]);
      s0 = __builtin_amdgcn_mfma_f32_16x16x32_bf16(aq[c], bk0, s0, 0, 0, 0);
      s1 = __builtin_amdgcn_mfma_f32_16x16x32_bf16(aq[c], bk1, s1, 0, 0, 0);
    }

    // C layout: q row = lg*4 + r, kv col = lr (verified m89/m91)
    const int k0i = kv0 + lr;
    const int k1i = kv0 + 16 + lr;
    const int pv0 = padb[k0i];
    const int pv1 = padb[k1i];
    float t0[4], t1[4], pm[4];
    #pragma unroll
    for (int r = 0; r < 4; ++r) {
      const int qi = q0 + lg * 4 + r;
      t0[r] = (k0i <= qi && pv0) ? s0[r] * SCALE_LOG2E : -__builtin_inff();
      t1[r] = (k1i <= qi && pv1) ? s1[r] * SCALE_LOG2E : -__builtin_inff();
      pm[r] = fmaxf(t0[r], t1[r]);
    }
    // row-max across the 16 lanes holding this row's 32 kv columns
    #pragma unroll
    for (int off = 1; off < 16; off <<= 1) {
      #pragma unroll
      for (int r = 0; r < 4; ++r)
        pm[r] = fmaxf(pm[r], __shfl_xor(pm[r], off, 64));
    }

    float al[4], ps[4];
    #pragma unroll
    for (int r = 0; r < 4; ++r) {
      const float mn = fmaxf(m_run[r], pm[r]);
      al[r] = exp2f(m_run[r] - mn);        // -inf -> 0 on first tile
      const float p0 = exp2f(t0[r] - mn);
      const float p1 = exp2f(t1[r] - mn);
      ps[r] = p0 + p1;
      m_run[r] = mn;
      P_lds[wid][lg * 4 + r][lr] = bf16r(p0);
      P_lds[wid][lg * 4 + r][16 + lr] = bf16r(p1);
    }
    #pragma unroll
    for (int off = 1; off < 16; off <<= 1) {
      #pragma unroll
      for (int r = 0; r < 4; ++r)
        ps[r] += __shfl_xor(ps[r], off, 64);
    }
    #pragma unroll
    for (int r = 0; r < 4; ++r) l_run[r] = l_run[r] * al[r] + ps[r];

    // rescale O accumulator
    #pragma unroll
    for (int dt = 0; dt < 8; ++dt) {
      #pragma unroll
      for (int r = 0; r < 4; ++r) o_acc[dt][r] *= al[r];
    }

    // PV: O(16x128) += P(16x32) . V(32x128); A from P_lds, B from Vt_lds
    short8 ap = *reinterpret_cast<const short8*>(&P_lds[wid][lr][lg * 8]);
    #pragma unroll
    for (int dt = 0; dt < 8; ++dt) {
      short8 bv = *reinterpret_cast<const short8*>(&Vt_lds[dt * 16 + lr][lg * 8]);
      o_acc[dt] = __builtin_amdgcn_mfma_f32_16x16x32_bf16(ap, bv, o_acc[dt], 0, 0, 0);
    }
  }

  // epilogue: normalize and store f32
  float inv[4];
  #pragma unroll
  for (int r = 0; r < 4; ++r) inv[r] = 1.f / l_run[r];
  #pragma unroll
  for (int dt = 0; dt < 8; ++dt) {
    #pragma unroll
    for (int r = 0; r < 4; ++r) {
      const int qi = q0 + lg * 4 + r;
      Og[base + (size_t)qi * Dc + dt * 16 + lr] = o_acc[dt][r] * inv[r];
    }
  }
}

extern "C" void kernel_launch(void* const* d_in, const int* in_sizes, int n_in,
                              void* d_out, int out_size, void* d_ws, size_t ws_size,
                              hipStream_t stream) {
  const float* q = (const float*)d_in[0];
  const float* k = (const float*)d_in[1];
  const float* v = (const float*)d_in[2];
  // d_in[3] = attn_mask (S x S tril) — implemented structurally via k<=q
  const int* pad = (const int*)d_in[4];
  float* out = (float*)d_out;
  dim3 grid(Sc / QT, Bc * Hc);
  attn_fwd_kernel<<<grid, dim3(256), 0, stream>>>(q, k, v, pad, out);
}

// Round 3
// 489.706 us; speedup vs baseline: 1.3146x; 1.3146x over previous
//
#include <hip/hip_runtime.h>
#include <hip/hip_bf16.h>

typedef __attribute__((ext_vector_type(8))) short short8;
typedef __attribute__((ext_vector_type(4))) short short4v;
typedef __attribute__((ext_vector_type(4))) float f32x4;

constexpr int Bc = 4, Hc = 16, Sc = 2048, Dc = 128;
constexpr int QT = 64;   // q rows per block (4 waves x 16)
constexpr int KT = 32;   // kv columns per tile
constexpr float SCALE_LOG2E = 0.08838834764831845f * 1.4426950408889634f;

__device__ inline ushort bf16r(float x) {
  __hip_bfloat16 h = __float2bfloat16(x);
  return *reinterpret_cast<ushort*>(&h);
}

// hardware transpose read: lane gets column ((addr&127)>>3) of the 128B-aligned
// 4x16 bf16 tile; elem j = tile_base_ushort + j*16 + slot (m156/m162 model)
#define TRRD(dst, offstr) \
  asm volatile("ds_read_b64_tr_b16 %0, %1 offset:" offstr : "=v"(dst) : "v"(ybase))

__global__ __launch_bounds__(256, 2)
void attn_fwd_kernel(const float* __restrict__ Qg, const float* __restrict__ Kg,
                     const float* __restrict__ Vg, const int* __restrict__ padg,
                     float* __restrict__ Og) {
  const int bh = blockIdx.y;
  const int b  = bh >> 4;                       // H = 16
  const int qt = (int)gridDim.x - 1 - (int)blockIdx.x;  // longest blocks first
  const int tid = threadIdx.x;
  const int wid = tid >> 6;
  const int lane = tid & 63;
  const int lg = lane >> 4;
  const int lr = lane & 15;

  const size_t base = (size_t)bh * Sc * Dc;
  const float* Qb = Qg + base;
  const float* Kb = Kg + base;
  const float* Vb = Vg + base;
  const int* padb = padg + b * Sc;

  __shared__ __align__(128) ushort Y_lds[8 * 8 * 64];  // V: [dsub][ksub][k&3][d&15]
  __shared__ ushort K_lds[KT][136];                    // row padded (+8)
  __shared__ ushort P_lds[4][16][40];                  // per-wave P, k'-slot columns

  const int q0 = qt * QT + wid * 16;

  // Q fragments (bf16-converted), lane holds Q[q0+lr][c*32 + lg*8 + i]
  short8 aq[4];
  #pragma unroll
  for (int c = 0; c < 4; ++c) {
    const float* gq = Qb + (size_t)(q0 + lr) * Dc + c * 32 + lg * 8;
    f32x4 qa = *reinterpret_cast<const f32x4*>(gq);
    f32x4 qc = *reinterpret_cast<const f32x4*>(gq + 4);
    short8 t;
    #pragma unroll
    for (int j = 0; j < 4; ++j) { t[j] = (short)bf16r(qa[j]); t[4 + j] = (short)bf16r(qc[j]); }
    aq[c] = t;
  }

  f32x4 o_acc[8];
  #pragma unroll
  for (int i = 0; i < 8; ++i) o_acc[i] = {0.f, 0.f, 0.f, 0.f};
  float m_run[4], l_run[4];
  #pragma unroll
  for (int r = 0; r < 4; ++r) { m_run[r] = -__builtin_inff(); l_run[r] = 0.f; }

  // staging assignment: thread -> (row sr, 16-wide d-chunk sc)
  const int sr = tid >> 3;
  const int sc = (tid & 7) * 16;
  const uint ybase = (uint)(size_t)(&Y_lds[0]) + (uint)((lg << 7) + (lr << 3));

  // prologue: prefetch tile 0 into registers
  f32x4 kreg[4], vreg[4];
  int curp0, curp1, nxtp0, nxtp1;
  {
    const float* gk = Kb + (size_t)sr * Dc + sc;
    const float* gv = Vb + (size_t)sr * Dc + sc;
    #pragma unroll
    for (int j = 0; j < 4; ++j) {
      kreg[j] = *reinterpret_cast<const f32x4*>(gk + j * 4);
      vreg[j] = *reinterpret_cast<const f32x4*>(gv + j * 4);
    }
    curp0 = padb[lr];
    curp1 = padb[16 + lr];
  }
  nxtp0 = curp0; nxtp1 = curp1;

  const int kv_end = qt * QT + QT;
  for (int kv0 = 0; kv0 < kv_end; kv0 += KT) {
    // barrier A: all waves finished reading prev tile's LDS (their reads were
    // consumed before reaching here). Raw barrier: no vmcnt drain.
    asm volatile("" ::: "memory");
    __builtin_amdgcn_s_barrier();
    asm volatile("" ::: "memory");

    // convert staged registers -> LDS (vmcnt wait auto-inserted at first use)
    {
      ushort tmp[16];
      #pragma unroll
      for (int j4 = 0; j4 < 4; ++j4)
        #pragma unroll
        for (int j = 0; j < 4; ++j) tmp[j4 * 4 + j] = bf16r(kreg[j4][j]);
      *reinterpret_cast<short8*>(&K_lds[sr][sc])     = *reinterpret_cast<const short8*>(&tmp[0]);
      *reinterpret_cast<short8*>(&K_lds[sr][sc + 8]) = *reinterpret_cast<const short8*>(&tmp[8]);
      #pragma unroll
      for (int j4 = 0; j4 < 4; ++j4)
        #pragma unroll
        for (int j = 0; j < 4; ++j) tmp[j4 * 4 + j] = bf16r(vreg[j4][j]);
      ushort* yp = &Y_lds[((sc >> 4) << 9) + ((sr >> 2) << 6) + ((sr & 3) << 4)];
      *reinterpret_cast<short8*>(yp)     = *reinterpret_cast<const short8*>(&tmp[0]);
      *reinterpret_cast<short8*>(yp + 8) = *reinterpret_cast<const short8*>(&tmp[8]);
    }

    // issue next tile's global loads; they stay in flight across the barrier
    if (kv0 + KT < kv_end) {
      const float* gk = Kb + (size_t)(kv0 + KT + sr) * Dc + sc;
      const float* gv = Vb + (size_t)(kv0 + KT + sr) * Dc + sc;
      #pragma unroll
      for (int j = 0; j < 4; ++j) {
        kreg[j] = *reinterpret_cast<const f32x4*>(gk + j * 4);
        vreg[j] = *reinterpret_cast<const f32x4*>(gv + j * 4);
      }
      nxtp0 = padb[kv0 + KT + lr];
      nxtp1 = padb[kv0 + KT + 16 + lr];
    }

    // barrier B: LDS writes visible to all waves; vmcnt NOT drained
    asm volatile("s_waitcnt lgkmcnt(0)" ::: "memory");
    __builtin_amdgcn_s_barrier();
    asm volatile("" ::: "memory");

    // ---- QK^T ----
    f32x4 s0 = {0.f, 0.f, 0.f, 0.f}, s1 = {0.f, 0.f, 0.f, 0.f};
    #pragma unroll
    for (int c = 0; c < 4; ++c) {
      short8 bk0 = *reinterpret_cast<const short8*>(&K_lds[lr][c * 32 + lg * 8]);
      short8 bk1 = *reinterpret_cast<const short8*>(&K_lds[16 + lr][c * 32 + lg * 8]);
      s0 = __builtin_amdgcn_mfma_f32_16x16x32_bf16(aq[c], bk0, s0, 0, 0, 0);
      s1 = __builtin_amdgcn_mfma_f32_16x16x32_bf16(aq[c], bk1, s1, 0, 0, 0);
    }

    // ---- masked online softmax (C layout: row = lg*4+r, col = lr) ----
    const int k0i = kv0 + lr;
    const int k1i = kv0 + 16 + lr;
    float t0[4], t1[4], pm[4];
    #pragma unroll
    for (int r = 0; r < 4; ++r) {
      const int qi = q0 + lg * 4 + r;
      t0[r] = (k0i <= qi && curp0) ? s0[r] * SCALE_LOG2E : -__builtin_inff();
      t1[r] = (k1i <= qi && curp1) ? s1[r] * SCALE_LOG2E : -__builtin_inff();
      pm[r] = fmaxf(t0[r], t1[r]);
    }
    #pragma unroll
    for (int off = 1; off < 16; off <<= 1)
      #pragma unroll
      for (int r = 0; r < 4; ++r)
        pm[r] = fmaxf(pm[r], __shfl_xor(pm[r], off, 64));

    // write P into k'-slot columns matching the tr-read k mapping:
    // k'<16 -> col (k'>>2)*8 + (k'&3); k'>=16 -> same + 4
    const int pc0 = ((lr >> 2) << 3) + (lr & 3);
    float al[4], ps[4];
    #pragma unroll
    for (int r = 0; r < 4; ++r) {
      const float mn = fmaxf(m_run[r], pm[r]);
      al[r] = exp2f(m_run[r] - mn);
      const float p0 = exp2f(t0[r] - mn);
      const float p1 = exp2f(t1[r] - mn);
      ps[r] = p0 + p1;
      m_run[r] = mn;
      P_lds[wid][lg * 4 + r][pc0]     = bf16r(p0);
      P_lds[wid][lg * 4 + r][pc0 + 4] = bf16r(p1);
    }
    #pragma unroll
    for (int off = 1; off < 16; off <<= 1)
      #pragma unroll
      for (int r = 0; r < 4; ++r)
        ps[r] += __shfl_xor(ps[r], off, 64);
    #pragma unroll
    for (int r = 0; r < 4; ++r) l_run[r] = l_run[r] * al[r] + ps[r];

    #pragma unroll
    for (int dt = 0; dt < 8; ++dt)
      #pragma unroll
      for (int r = 0; r < 4; ++r) o_acc[dt][r] *= al[r];

    // ---- PV via hardware transpose reads of V ----
    short8 ap = *reinterpret_cast<const short8*>(&P_lds[wid][lr][lg * 8]);
    short4v ta[8];
    TRRD(ta[0], "0");    TRRD(ta[1], "512");
    TRRD(ta[2], "1024"); TRRD(ta[3], "1536");
    TRRD(ta[4], "2048"); TRRD(ta[5], "2560");
    TRRD(ta[6], "3072"); TRRD(ta[7], "3584");
    asm volatile("s_waitcnt lgkmcnt(0)" ::: "memory");
    __builtin_amdgcn_sched_barrier(0);
    #pragma unroll
    for (int dt = 0; dt < 4; ++dt) {
      short8 bv = __builtin_shufflevector(ta[2 * dt], ta[2 * dt + 1], 0, 1, 2, 3, 4, 5, 6, 7);
      o_acc[dt] = __builtin_amdgcn_mfma_f32_16x16x32_bf16(ap, bv, o_acc[dt], 0, 0, 0);
    }
    TRRD(ta[0], "4096"); TRRD(ta[1], "4608");
    TRRD(ta[2], "5120"); TRRD(ta[3], "5632");
    TRRD(ta[4], "6144"); TRRD(ta[5], "6656");
    TRRD(ta[6], "7168"); TRRD(ta[7], "7680");
    asm volatile("s_waitcnt lgkmcnt(0)" ::: "memory");
    __builtin_amdgcn_sched_barrier(0);
    #pragma unroll
    for (int dt = 4; dt < 8; ++dt) {
      short8 bv = __builtin_shufflevector(ta[2 * (dt - 4)], ta[2 * (dt - 4) + 1], 0, 1, 2, 3, 4, 5, 6, 7);
      o_acc[dt] = __builtin_amdgcn_mfma_f32_16x16x32_bf16(ap, bv, o_acc[dt], 0, 0, 0);
    }

    curp0 = nxtp0; curp1 = nxtp1;
  }

  // epilogue: normalize and store f32
  float inv[4];
  #pragma unroll
  for (int r = 0; r < 4; ++r) inv[r] = 1.f / l_run[r];
  #pragma unroll
  for (int dt = 0; dt < 8; ++dt) {
    #pragma unroll
    for (int r = 0; r < 4; ++r) {
      const int qi = q0 + lg * 4 + r;
      Og[base + (size_t)qi * Dc + dt * 16 + lr] = o_acc[dt][r] * inv[r];
    }
  }
}

extern "C" void kernel_launch(void* const* d_in, const int* in_sizes, int n_in,
                              void* d_out, int out_size, void* d_ws, size_t ws_size,
                              hipStream_t stream) {
  const float* q = (const float*)d_in[0];
  const float* k = (const float*)d_in[1];
  const float* v = (const float*)d_in[2];
  // d_in[3] = attn_mask (S x S tril) — implemented structurally via k<=q
  const int* pad = (const int*)d_in[4];
  float* out = (float*)d_out;
  dim3 grid(Sc / QT, Bc * Hc);
  attn_fwd_kernel<<<grid, dim3(256), 0, stream>>>(q, k, v, pad, out);
}